// Round 1
// baseline (6164.306 us; speedup 1.0000x reference)
//
#include <hip/hip_runtime.h>
#include <hip/hip_bf16.h>

#define Bn 64
#define Tn 1024
#define In 64
#define Dn 256

typedef short bf16x8 __attribute__((ext_vector_type(8)));
typedef unsigned short u16x8 __attribute__((ext_vector_type(8)));
typedef unsigned short u16x4 __attribute__((ext_vector_type(4)));
typedef float f32x4 __attribute__((ext_vector_type(4)));

__device__ __forceinline__ unsigned short f2bf(float f){
  unsigned u = __float_as_uint(f);
  u += 0x7fffu + ((u >> 16) & 1u);       // RNE
  return (unsigned short)(u >> 16);
}
__device__ __forceinline__ float sig_(float x){ return 1.f / (1.f + __expf(-x)); }
__device__ __forceinline__ float tanh_(float x){ float e = __expf(2.f * x); return 1.f - 2.f / (e + 1.f); }

// ---------------------------------------------------------------------------
// LSTM: 64 batches x 4 parts. Part p owns h dims [p*64, p*64+64).
// W_hh slice lives in fp32 registers (rotated so own block is first).
// h exchanged through agent-scope global buffer, double-buffered by t&1.
// ---------------------------------------------------------------------------
__global__ __launch_bounds__(256, 1) void lstm_kernel(
    const float* __restrict__ x, const float* __restrict__ Wih,
    const float* __restrict__ Whh, const float* __restrict__ bih,
    const float* __restrict__ bhh, unsigned short* __restrict__ Hbf,
    float* __restrict__ hglob, int* __restrict__ progress)
{
  const int wg = blockIdx.x;
  const int b = wg & 63;          // parts of batch b land on same XCD (wg%8==b%8)
  const int p = wg >> 6;
  const int p64 = p * 64;
  const int j = threadIdx.x;
  const int gate = j >> 6, dl = j & 63;
  const int grow = gate * Dn + p64 + dl;   // global gate row (i,f,g,o blocks)

  float wih[In];
  float whhR[Dn];                 // rotated: whhR[k] = Whh[grow][(p64+k)&255]
  #pragma unroll
  for (int k = 0; k < In; ++k) wih[k] = Wih[grow * In + k];
  #pragma unroll
  for (int k = 0; k < Dn; ++k) whhR[k] = Whh[grow * Dn + ((p64 + k) & (Dn - 1))];
  const float bias = bih[grow] + bhh[grow];

  __shared__ float lds_x[In];
  __shared__ float lds_hd[2 * Dn];   // duplicated so [p64 .. p64+255] is contiguous
  __shared__ float lds_g[256];
  __shared__ float lds_c[64];

  lds_hd[j] = 0.f; lds_hd[j + Dn] = 0.f;
  if (j < 64) lds_c[j] = 0.f;
  __syncthreads();

  const int pb = b * 4;
  const int peer = pb + ((j < 3) ? (j + (j >= p ? 1 : 0)) : 0);

  for (int t = 0; t < Tn; ++t){
    if (j < In) lds_x[j] = x[(b * Tn + t) * In + j];
    __syncthreads();                                    // B0: x ready, prev iter done
    // overlap with peer wait: x part + own h block
    float acc = bias;
    #pragma unroll
    for (int k = 0; k < In; ++k) acc += wih[k] * lds_x[k];
    #pragma unroll
    for (int k = 0; k < 64; ++k) acc += whhR[k] * lds_hd[p64 + k];
    if (t > 0 && j < 3){
      while (__hip_atomic_load(&progress[peer], __ATOMIC_ACQUIRE, __HIP_MEMORY_SCOPE_AGENT) < t) {}
    }
    __syncthreads();                                    // B1: peers' h(t-1) committed
    if (t > 0 && j < 192){
      const int dim = (j < p64) ? j : (j + 64);
      float hv = __hip_atomic_load(&hglob[(b * 2 + ((t - 1) & 1)) * Dn + dim],
                                   __ATOMIC_RELAXED, __HIP_MEMORY_SCOPE_AGENT);
      lds_hd[dim] = hv; lds_hd[dim + Dn] = hv;
    }
    __syncthreads();                                    // B2: lds_hd complete
    #pragma unroll
    for (int k = 64; k < Dn; ++k) acc += whhR[k] * lds_hd[p64 + k];
    lds_g[j] = acc;
    __syncthreads();                                    // B3: gates ready
    if (j < 64){
      const float ig = sig_(lds_g[j]);
      const float fg = sig_(lds_g[64 + j]);
      const float gg = tanh_(lds_g[128 + j]);
      const float og = sig_(lds_g[192 + j]);
      const float c = fg * lds_c[j] + ig * gg;
      lds_c[j] = c;
      const float h = og * tanh_(c);
      const int dim = p64 + j;
      lds_hd[dim] = h; lds_hd[dim + Dn] = h;
      __hip_atomic_store(&hglob[(b * 2 + (t & 1)) * Dn + dim], h,
                         __ATOMIC_RELAXED, __HIP_MEMORY_SCOPE_AGENT);
      Hbf[(b * Tn + t) * Dn + dim] = f2bf(h);
    }
    __syncthreads();                                    // B4: stores drained (vmcnt @ barrier)
    if (j == 0)
      __hip_atomic_store(&progress[pb + p], t + 1, __ATOMIC_RELEASE, __HIP_MEMORY_SCOPE_AGENT);
  }
}

// ---------------------------------------------------------------------------
// Flash attention, Q=K=V=H (bf16), unscaled, causal. One WG per (b, 64-row qtile).
// ---------------------------------------------------------------------------
__global__ __launch_bounds__(256, 1) void attn_kernel(
    const unsigned short* __restrict__ Hbf, unsigned short* __restrict__ ctxbf)
{
  const int bid = blockIdx.x;
  const int b = bid >> 4, qt = bid & 15;
  const int q0 = qt * 64;
  const int tid = threadIdx.x;
  const int w = tid >> 6, l = tid & 63;
  const int lr = l & 15, lg = l >> 4;

  __shared__ unsigned short Qs[64 * 256];
  __shared__ unsigned short Ks[64 * 256];
  __shared__ unsigned short Vt[256 * 64];   // transposed: [d][s]
  __shared__ unsigned short Ps[64 * 64];

  {
    const int r = tid >> 2, cs = (tid & 3) * 64;
    #pragma unroll
    for (int jj = 0; jj < 8; ++jj){
      const int c = cs + jj * 8;
      u16x8 v = *(const u16x8*)&Hbf[(b * Tn + q0 + r) * Dn + c];
      *(u16x8*)((char*)Qs + (((r * 256 + c) * 2) ^ ((r & 7) << 4))) = v;
    }
  }
  __syncthreads();
  bf16x8 qf[8];
  #pragma unroll
  for (int kc = 0; kc < 8; ++kc){
    const int r = w * 16 + lr, c = kc * 32 + lg * 8;
    qf[kc] = *(const bf16x8*)((const char*)Qs + (((r * 256 + c) * 2) ^ ((r & 7) << 4)));
  }

  float m_i[4], l_i[4];
  f32x4 o_acc[16];
  #pragma unroll
  for (int i = 0; i < 4; ++i){ m_i[i] = -__builtin_inff(); l_i[i] = 0.f; }
  #pragma unroll
  for (int n = 0; n < 16; ++n) o_acc[n] = (f32x4){0.f, 0.f, 0.f, 0.f};

  for (int kt = 0; kt <= qt; ++kt){
    const int s0 = kt * 64;
    __syncthreads();    // previous-iteration K/Vt consumers done
    {
      const int r = tid >> 2, cs = (tid & 3) * 64;
      #pragma unroll
      for (int jj = 0; jj < 8; ++jj){
        const int c = cs + jj * 8;
        u16x8 v = *(const u16x8*)&Hbf[(b * Tn + s0 + r) * Dn + c];
        *(u16x8*)((char*)Ks + (((r * 256 + c) * 2) ^ ((r & 7) << 4))) = v;
      }
    }
    {
      const int s = tid & 63, db = tid >> 6;
      #pragma unroll
      for (int jj = 0; jj < 8; ++jj){
        const int d0 = db * 64 + jj * 8;
        u16x8 v = *(const u16x8*)&Hbf[(b * Tn + s0 + s) * Dn + d0];
        #pragma unroll
        for (int e = 0; e < 8; ++e){
          const int d = d0 + e;
          *(unsigned short*)((char*)Vt + (((d * 64 + s) * 2) ^ ((d & 7) << 4))) = (unsigned short)v[e];
        }
      }
    }
    __syncthreads();
    // S = Q K^T for this wave's 16 q-rows
    f32x4 sacc[4];
    #pragma unroll
    for (int n = 0; n < 4; ++n) sacc[n] = (f32x4){0.f, 0.f, 0.f, 0.f};
    #pragma unroll
    for (int kc = 0; kc < 8; ++kc){
      #pragma unroll
      for (int n = 0; n < 4; ++n){
        const int r = n * 16 + lr, c = kc * 32 + lg * 8;
        bf16x8 kfr = *(const bf16x8*)((const char*)Ks + (((r * 256 + c) * 2) ^ ((r & 7) << 4)));
        sacc[n] = __builtin_amdgcn_mfma_f32_16x16x32_bf16(qf[kc], kfr, sacc[n], 0, 0, 0);
      }
    }
    if (kt == qt){
      #pragma unroll
      for (int n = 0; n < 4; ++n)
        #pragma unroll
        for (int i = 0; i < 4; ++i){
          const int scol = s0 + n * 16 + lr;
          const int qrow = q0 + w * 16 + lg * 4 + i;
          if (scol > qrow) sacc[n][i] = -__builtin_inff();
        }
    }
    float rmax[4], alpha[4], rsum[4];
    #pragma unroll
    for (int i = 0; i < 4; ++i){
      float v = fmaxf(fmaxf(sacc[0][i], sacc[1][i]), fmaxf(sacc[2][i], sacc[3][i]));
      v = fmaxf(v, __shfl_xor(v, 1));
      v = fmaxf(v, __shfl_xor(v, 2));
      v = fmaxf(v, __shfl_xor(v, 4));
      v = fmaxf(v, __shfl_xor(v, 8));
      rmax[i] = v;
    }
    #pragma unroll
    for (int i = 0; i < 4; ++i){
      const float mn = fmaxf(m_i[i], rmax[i]);
      alpha[i] = __expf(m_i[i] - mn);
      m_i[i] = mn;
      rsum[i] = 0.f;
    }
    #pragma unroll
    for (int n = 0; n < 4; ++n){
      #pragma unroll
      for (int i = 0; i < 4; ++i){
        const float pv = __expf(sacc[n][i] - m_i[i]);   // exp(-inf)=0 handles mask
        rsum[i] += pv;
        const int r = w * 16 + lg * 4 + i, c = n * 16 + lr;
        *(unsigned short*)((char*)Ps + (((r * 64 + c) * 2) ^ ((r & 7) << 4))) = f2bf(pv);
      }
    }
    #pragma unroll
    for (int i = 0; i < 4; ++i){
      float v = rsum[i];
      v += __shfl_xor(v, 1);
      v += __shfl_xor(v, 2);
      v += __shfl_xor(v, 4);
      v += __shfl_xor(v, 8);
      l_i[i] = l_i[i] * alpha[i] + v;
    }
    #pragma unroll
    for (int n = 0; n < 16; ++n)
      #pragma unroll
      for (int i = 0; i < 4; ++i) o_acc[n][i] *= alpha[i];
    // PV: each wave reads only its own P rows (same-wave LDS dep, compiler waits lgkmcnt)
    #pragma unroll
    for (int kc = 0; kc < 2; ++kc){
      const int r = w * 16 + lr, c = kc * 32 + lg * 8;
      bf16x8 pfr = *(const bf16x8*)((const char*)Ps + (((r * 64 + c) * 2) ^ ((r & 7) << 4)));
      #pragma unroll
      for (int n = 0; n < 16; ++n){
        const int vr = n * 16 + lr, vc = kc * 32 + lg * 8;
        bf16x8 vfr = *(const bf16x8*)((const char*)Vt + (((vr * 64 + vc) * 2) ^ ((vr & 7) << 4)));
        o_acc[n] = __builtin_amdgcn_mfma_f32_16x16x32_bf16(pfr, vfr, o_acc[n], 0, 0, 0);
      }
    }
  }
  #pragma unroll
  for (int n = 0; n < 16; ++n)
    #pragma unroll
    for (int i = 0; i < 4; ++i){
      const float v = o_acc[n][i] / l_i[i];
      const int q = q0 + w * 16 + lg * 4 + i;
      const int d = n * 16 + lr;
      ctxbf[(b * Tn + q) * Dn + d] = f2bf(v);
    }
}

// ---------------------------------------------------------------------------
// MLP: out = relu([H|ctx] @ W1^T + b1) @ W2^T + b2, fused per 64-row M tile.
// ---------------------------------------------------------------------------
__global__ __launch_bounds__(256, 1) void mlp_kernel(
    const unsigned short* __restrict__ Hbf, const unsigned short* __restrict__ ctxbf,
    const float* __restrict__ W1, const float* __restrict__ b1,
    const float* __restrict__ W2, const float* __restrict__ b2,
    float* __restrict__ out)
{
  const int m0 = blockIdx.x * 64;
  const int tid = threadIdx.x;
  const int w = tid >> 6, l = tid & 63;
  const int lr = l & 15, lg = l >> 4;

  __shared__ unsigned short As[64 * 512];
  __shared__ unsigned short Ws[64 * 512];

  {
    const int r = tid >> 2, cs = (tid & 3) * 128;
    #pragma unroll
    for (int jj = 0; jj < 16; ++jj){
      const int c = cs + jj * 8;
      u16x8 v;
      if (c < 256) v = *(const u16x8*)&Hbf[(m0 + r) * Dn + c];
      else         v = *(const u16x8*)&ctxbf[(m0 + r) * Dn + (c - 256)];
      *(u16x8*)((char*)As + (((r * 512 + c) * 2) ^ ((r & 7) << 4))) = v;
    }
  }
  f32x4 hacc[16];
  #pragma unroll
  for (int n = 0; n < 16; ++n) hacc[n] = (f32x4){0.f, 0.f, 0.f, 0.f};

  for (int nb = 0; nb < 4; ++nb){
    __syncthreads();
    {
      const int r = tid >> 2, cs = (tid & 3) * 128;
      #pragma unroll
      for (int jj = 0; jj < 32; ++jj){
        const int c = cs + jj * 4;
        const float4 v = *(const float4*)&W1[(nb * 64 + r) * 512 + c];
        u16x4 pk = { f2bf(v.x), f2bf(v.y), f2bf(v.z), f2bf(v.w) };
        *(u16x4*)((char*)Ws + (((r * 512 + c) * 2) ^ ((r & 7) << 4))) = pk;
      }
    }
    __syncthreads();
    #pragma unroll
    for (int kc = 0; kc < 16; ++kc){
      const int ar = w * 16 + lr, ac = kc * 32 + lg * 8;
      bf16x8 af = *(const bf16x8*)((const char*)As + (((ar * 512 + ac) * 2) ^ ((ar & 7) << 4)));
      #pragma unroll
      for (int n = 0; n < 4; ++n){
        const int br = n * 16 + lr;
        bf16x8 bf = *(const bf16x8*)((const char*)Ws + (((br * 512 + ac) * 2) ^ ((br & 7) << 4)));
        hacc[nb * 4 + n] = __builtin_amdgcn_mfma_f32_16x16x32_bf16(af, bf, hacc[nb * 4 + n], 0, 0, 0);
      }
    }
  }
  __syncthreads();
  // relu + b1 -> hid (bf16) into As as [64][256]
  #pragma unroll
  for (int nn = 0; nn < 16; ++nn){
    const int col = (nn >> 2) * 64 + (nn & 3) * 16 + lr;
    const float bv = b1[col];
    #pragma unroll
    for (int i = 0; i < 4; ++i){
      float v = hacc[nn][i] + bv;
      v = v > 0.f ? v : 0.f;
      const int r = w * 16 + lg * 4 + i;
      *(unsigned short*)((char*)As + (((r * 256 + col) * 2) ^ ((r & 7) << 4))) = f2bf(v);
    }
  }
  {
    const int r = tid >> 2, cs = (tid & 3) * 64;
    #pragma unroll
    for (int jj = 0; jj < 16; ++jj){
      const int c = cs + jj * 4;
      const float4 v = *(const float4*)&W2[r * 256 + c];
      u16x4 pk = { f2bf(v.x), f2bf(v.y), f2bf(v.z), f2bf(v.w) };
      *(u16x4*)((char*)Ws + (((r * 256 + c) * 2) ^ ((r & 7) << 4))) = pk;
    }
  }
  __syncthreads();
  f32x4 oacc[4];
  #pragma unroll
  for (int n = 0; n < 4; ++n) oacc[n] = (f32x4){0.f, 0.f, 0.f, 0.f};
  #pragma unroll
  for (int kc = 0; kc < 8; ++kc){
    const int ar = w * 16 + lr, ac = kc * 32 + lg * 8;
    bf16x8 af = *(const bf16x8*)((const char*)As + (((ar * 256 + ac) * 2) ^ ((ar & 7) << 4)));
    #pragma unroll
    for (int n = 0; n < 4; ++n){
      const int br = n * 16 + lr;
      bf16x8 bf = *(const bf16x8*)((const char*)Ws + (((br * 256 + ac) * 2) ^ ((br & 7) << 4)));
      oacc[n] = __builtin_amdgcn_mfma_f32_16x16x32_bf16(af, bf, oacc[n], 0, 0, 0);
    }
  }
  #pragma unroll
  for (int n = 0; n < 4; ++n)
    #pragma unroll
    for (int i = 0; i < 4; ++i){
      const int ii = n * 16 + lr;
      const int m = m0 + w * 16 + lg * 4 + i;
      out[m * In + ii] = oacc[n][i] + b2[ii];
    }
}

extern "C" void kernel_launch(void* const* d_in, const int* in_sizes, int n_in,
                              void* d_out, int out_size, void* d_ws, size_t ws_size,
                              hipStream_t stream)
{
  (void)in_sizes; (void)n_in; (void)out_size; (void)ws_size;
  const float* x   = (const float*)d_in[0];
  const float* Wih = (const float*)d_in[1];
  const float* Whh = (const float*)d_in[2];
  const float* bih = (const float*)d_in[3];
  const float* bhh = (const float*)d_in[4];
  const float* W1  = (const float*)d_in[5];
  const float* b1  = (const float*)d_in[6];
  const float* W2  = (const float*)d_in[7];
  const float* b2  = (const float*)d_in[8];
  float* out = (float*)d_out;

  char* ws = (char*)d_ws;
  unsigned short* Hbf   = (unsigned short*)ws;                           // 32 MB
  unsigned short* ctxbf = (unsigned short*)(ws + (size_t)32 * 1024 * 1024); // 32 MB
  float* hglob = (float*)(ws + (size_t)64 * 1024 * 1024);                // 128 KB
  int* progress = (int*)(ws + (size_t)64 * 1024 * 1024 + 256 * 1024);    // 1 KB

  hipMemsetAsync(progress, 0, 256 * sizeof(int), stream);
  lstm_kernel<<<256, 256, 0, stream>>>(x, Wih, Whh, bih, bhh, Hbf, hglob, progress);
  attn_kernel<<<Bn * 16, 256, 0, stream>>>(Hbf, ctxbf);
  mlp_kernel<<<(Bn * Tn) / 64, 256, 0, stream>>>(Hbf, ctxbf, W1, b1, W2, b2, out);
}